// Round 17
// baseline (45.031 us; speedup 1.0000x reference)
//
#include <hip/hip_runtime.h>
#include <hip/hip_bf16.h>
#include <math.h>

// Problem constants
#define B_DIM 2
#define L_SEQ 2048
#define D_DIM 256
#define N_DIM 64
#define K_CONV 4
#define M_ROWS (B_DIM * L_SEQ)   // 4096
#define NC 64                     // number of scan chunks
#define CL (L_SEQ / NC)           // 32 steps per chunk

typedef __attribute__((ext_vector_type(8))) short bf16x8;
typedef __attribute__((ext_vector_type(4))) float f32x4;
typedef unsigned short ushort_t;

// f32 -> bf16 (RNE) through the compiler's cvt path (pattern-matches to
// v_cvt_pk_bf16_f32 — hand-rolled bit math defeats that).
static __device__ __forceinline__ ushort_t f2bf(float f) {
  __hip_bfloat16 h = __float2bfloat16(f);
  return *reinterpret_cast<ushort_t*>(&h);
}
static __device__ __forceinline__ float bf2f(ushort_t s) {
  return __uint_as_float(((unsigned int)s) << 16);
}
static __device__ __forceinline__ unsigned int pack2(float a, float b) {
  __hip_bfloat162 h = __float22bfloat162_rn(make_float2(a, b));
  return *reinterpret_cast<unsigned int*>(&h);
}

// ====== K1: proj = x @ W_in^T (inline f32->bf16 staging) + weight cvt ======
// blocks 0..511: 64x64 GEMM tiles, XCD-swizzled (bm = bid&63 -> same-panel
// blocks share an XCD; row panel p lives on XCD p%8).
// blocks 512..671: convert W_bc/W_lam/W_out to bf16.
__global__ __launch_bounds__(256) void projcvt64(
    const float* __restrict__ x, const float* __restrict__ wi,
    const float* __restrict__ wbc, const float* __restrict__ wl,
    const float* __restrict__ wo,
    ushort_t* __restrict__ wbcb, ushort_t* __restrict__ wlb,
    ushort_t* __restrict__ wob,
    ushort_t* __restrict__ skipb, ushort_t* __restrict__ praw) {
  const int bid = blockIdx.x;
  const int tid = threadIdx.x;
  if (bid >= 512) {                 // ---- converter blocks ----
    int vb = bid - 512;
    const float* src; ushort_t* dst; int off;
    if (vb < 32)      { src = wbc; dst = wbcb; off = vb; }
    else if (vb < 96) { src = wl;  dst = wlb;  off = vb - 32; }
    else              { src = wo;  dst = wob;  off = vb - 96; }
    size_t i = (size_t)off * 1024 + tid * 4;
    float4 v = *reinterpret_cast<const float4*>(&src[i]);
    uint2 o;
    o.x = pack2(v.x, v.y);
    o.y = pack2(v.z, v.w);
    *reinterpret_cast<uint2*>(&dst[i]) = o;
    return;
  }
  // ---- GEMM block ----
  __shared__ __align__(16) ushort_t As[64][72];
  __shared__ __align__(16) ushort_t Ws[64][72];
  const int lane = tid & 63;
  const int w = tid >> 6;
  const int wm = w >> 1;
  const int wn = w & 1;
  const int bm = (bid & 63) * 64;
  const int bn = (bid >> 6) * 64;
  const int r0 = tid >> 3;          // 0..31
  const int c8 = (tid & 7) * 8;
  const int row16 = lane & 15;

  f32x4 acc[2][2];
  #pragma unroll
  for (int i = 0; i < 2; ++i)
    #pragma unroll
    for (int j = 0; j < 2; ++j)
      acc[i][j] = (f32x4){0.f, 0.f, 0.f, 0.f};

  for (int k0 = 0; k0 < 256; k0 += 64) {
    #pragma unroll
    for (int p = 0; p < 2; ++p) {
      int r = r0 + p * 32;
      const float* src = &x[(size_t)(bm + r) * 256 + k0 + c8];
      float4 v0 = *reinterpret_cast<const float4*>(src);
      float4 v1 = *reinterpret_cast<const float4*>(src + 4);
      uint4 o;
      o.x = pack2(v0.x, v0.y); o.y = pack2(v0.z, v0.w);
      o.z = pack2(v1.x, v1.y); o.w = pack2(v1.z, v1.w);
      *reinterpret_cast<uint4*>(&As[r][c8]) = o;
      const float* srcw = &wi[(size_t)(bn + r) * 256 + k0 + c8];
      float4 w0 = *reinterpret_cast<const float4*>(srcw);
      float4 w1 = *reinterpret_cast<const float4*>(srcw + 4);
      uint4 ow;
      ow.x = pack2(w0.x, w0.y); ow.y = pack2(w0.z, w0.w);
      ow.z = pack2(w1.x, w1.y); ow.w = pack2(w1.z, w1.w);
      *reinterpret_cast<uint4*>(&Ws[r][c8]) = ow;
    }
    __syncthreads();
    #pragma unroll
    for (int ks = 0; ks < 2; ++ks) {
      const int ko = ks * 32 + (lane >> 4) * 8;
      bf16x8 af[2], bfr[2];
      #pragma unroll
      for (int i = 0; i < 2; ++i)
        af[i] = *reinterpret_cast<const bf16x8*>(&As[wm * 32 + i * 16 + row16][ko]);
      #pragma unroll
      for (int j = 0; j < 2; ++j)
        bfr[j] = *reinterpret_cast<const bf16x8*>(&Ws[wn * 32 + j * 16 + row16][ko]);
      #pragma unroll
      for (int i = 0; i < 2; ++i)
        #pragma unroll
        for (int j = 0; j < 2; ++j)
          acc[i][j] = __builtin_amdgcn_mfma_f32_16x16x32_bf16(af[i], bfr[j], acc[i][j], 0, 0, 0);
    }
    __syncthreads();
  }

  const int cl = lane & 15;
  const int rg = lane >> 4;
  #pragma unroll
  for (int j = 0; j < 2; ++j) {
    const int col = bn + wn * 32 + j * 16 + cl;
    ushort_t* dst = (col < 256) ? skipb : praw;
    const int cc = col & 255;
    #pragma unroll
    for (int i = 0; i < 2; ++i) {
      const int rbase = bm + wm * 32 + i * 16 + rg * 4;
      #pragma unroll
      for (int rr = 0; rr < 4; ++rr)
        dst[(size_t)(rbase + rr) * 256 + cc] = f2bf(acc[i][j][rr]);
    }
  }
}

// ====== K2: depthwise conv (into LDS) + bc|lambda GEMM, 64-row panels ======
// bm = (bid&63)*64 -> row panel bid&63 stays on XCD (bid&63)%8 = producer's.
__global__ __launch_bounds__(256) void convbclam(
    const ushort_t* __restrict__ praw, const float* __restrict__ cw,
    const float* __restrict__ cb,
    const ushort_t* __restrict__ wbcb, const ushort_t* __restrict__ wlb,
    const float* __restrict__ b_bc, const float* __restrict__ b_lam,
    const float* __restrict__ Avec,
    ushort_t* __restrict__ bcbf, float* __restrict__ lamb,
    ushort_t* __restrict__ uwb) {
  __shared__ __align__(16) ushort_t Us[64][264];    // 33.8 KB
  __shared__ __align__(16) ushort_t Ws[64][72];     // 9.2 KB
  const int tid = threadIdx.x;
  const int lane = tid & 63;
  const int w = tid >> 6;
  const int wm = w >> 1;
  const int wn = w & 1;
  const int bid = blockIdx.x;
  const int bm = (bid & 63) * 64;
  const int bn = (bid >> 6) * 64;    // 0..5 tiles

  {
    const int d = tid;
    const float4 w4 = *reinterpret_cast<const float4*>(&cw[d * 4]);
    const float bias = cb[d];
    const bool edge = (bm & 2047) == 0;   // batch boundary
    float p0 = edge ? 0.f : bf2f(praw[(size_t)(bm - 3) * 256 + d]);
    float p1 = edge ? 0.f : bf2f(praw[(size_t)(bm - 2) * 256 + d]);
    float p2 = edge ? 0.f : bf2f(praw[(size_t)(bm - 1) * 256 + d]);
    #pragma unroll 8
    for (int r = 0; r < 64; ++r) {
      float p3 = bf2f(praw[(size_t)(bm + r) * 256 + d]);
      float u = bias + w4.x * p0 + w4.y * p1 + w4.z * p2 + w4.w * p3;
      Us[r][d] = f2bf(u);
      p0 = p1; p1 = p2; p2 = p3;
    }
  }
  __syncthreads();

  const ushort_t* Wsrc = (bn < 128) ? (wbcb + (size_t)bn * 256)
                                    : (wlb + (size_t)(bn - 128) * 256);
  const int r0 = tid >> 3;
  const int c8 = (tid & 7) * 8;
  const int row16 = lane & 15;

  f32x4 acc[2][2];
  #pragma unroll
  for (int i = 0; i < 2; ++i)
    #pragma unroll
    for (int j = 0; j < 2; ++j)
      acc[i][j] = (f32x4){0.f, 0.f, 0.f, 0.f};

  for (int k0 = 0; k0 < 256; k0 += 64) {
    #pragma unroll
    for (int p = 0; p < 2; ++p) {
      int r = r0 + p * 32;
      uint4 v = *reinterpret_cast<const uint4*>(&Wsrc[(size_t)r * 256 + k0 + c8]);
      *reinterpret_cast<uint4*>(&Ws[r][c8]) = v;
    }
    __syncthreads();
    #pragma unroll
    for (int ks = 0; ks < 2; ++ks) {
      const int ko = ks * 32 + (lane >> 4) * 8;
      bf16x8 af[2], bfr[2];
      #pragma unroll
      for (int i = 0; i < 2; ++i)
        af[i] = *reinterpret_cast<const bf16x8*>(&Us[wm * 32 + i * 16 + row16][k0 + ko]);
      #pragma unroll
      for (int j = 0; j < 2; ++j)
        bfr[j] = *reinterpret_cast<const bf16x8*>(&Ws[wn * 32 + j * 16 + row16][ko]);
      #pragma unroll
      for (int i = 0; i < 2; ++i)
        #pragma unroll
        for (int j = 0; j < 2; ++j)
          acc[i][j] = __builtin_amdgcn_mfma_f32_16x16x32_bf16(af[i], bfr[j], acc[i][j], 0, 0, 0);
    }
    __syncthreads();
  }

  const int cl = lane & 15;
  const int rg = lane >> 4;
  #pragma unroll
  for (int j = 0; j < 2; ++j) {
    const int col = bn + wn * 32 + j * 16 + cl;
    if (col < 128) {
      const float bv = b_bc[col];
      #pragma unroll
      for (int i = 0; i < 2; ++i) {
        const int rbase = bm + wm * 32 + i * 16 + rg * 4;
        #pragma unroll
        for (int rr = 0; rr < 4; ++rr)
          bcbf[(size_t)(rbase + rr) * 128 + col] = f2bf(acc[i][j][rr] + bv);
      }
    } else {
      const int dd = col - 128;
      const float bv = b_lam[dd];
      const float adg = -8.f * log1pf(__expf(Avec[dd]));
      #pragma unroll
      for (int i = 0; i < 2; ++i) {
        const int rbase = bm + wm * 32 + i * 16 + rg * 4;
        #pragma unroll
        for (int rr = 0; rr < 4; ++rr) {
          const int row = rbase + rr;
          float v = acc[i][j][rr] + bv;
          float s = 1.f / (1.f + __expf(-v));
          float lam = __expf(s * adg);
          float wq = sqrtf(1.f + 1e-6f - lam * lam);
          float u = bf2f(Us[row - bm][dd]);
          lamb[(size_t)row * 256 + dd] = lam;
          uwb[(size_t)row * 256 + dd] = f2bf(u * wq);
        }
      }
    }
  }
}

// ---- producer-aligned decode for the scan kernels -------------------------
// Chunk c occupies row panel c/2, produced on XCD (c/2)%8. Map blocks so
// chunk c runs on XCD (c/2)%8: xcd = bid&7, c = 2*(xcd + 8*pair) + parity.
static __device__ __forceinline__ void scan_decode(
    int bid, int& b, int& c, int& dq) {
  const int xcd = bid & 7;
  const int idx = bid >> 3;      // 0..63
  b = idx >> 5;                  // 0..1
  const int rem = idx & 31;      // 0..31
  c = 2 * (xcd + 8 * (rem & 3)) + ((rem >> 2) & 1);
  dq = (rem >> 3) & 3;
}

// ====== K3: chunk-local scan via MFMA (chunked linear attention) ===========
__global__ __launch_bounds__(256) void passA_mfma(
    const float* __restrict__ lamb, const ushort_t* __restrict__ uwb,
    const ushort_t* __restrict__ bcbf, float* __restrict__ Pc,
    ushort_t* __restrict__ Hc, ushort_t* __restrict__ ylocal) {
  int b, c, dq;
  scan_decode(blockIdx.x, b, c, dq);
  const int tid = threadIdx.x;
  const int lane = tid & 63;
  const int w = tid >> 6;
  const int row16 = lane & 15;
  const int cl = lane & 15;
  const int rg = lane >> 4;

  __shared__ __align__(16) ushort_t bcs[CL][136];  // [t][0..63]=b, [64..127]=c
  __shared__ __align__(16) float    Ls[CL][68];    // lam -> cumprod (in place)
  __shared__ __align__(16) ushort_t uws[CL][72];
  __shared__ __align__(16) ushort_t VT[64][40];    // V^T[d][tau]
  __shared__ __align__(16) ushort_t bT[64][40];    // b^T[n][tau]
  __shared__ __align__(16) ushort_t GL[CL][40];    // tril(G)[t][tau]
  __shared__ float segp[4][68];

  {
    const int r = tid >> 3;
    const int q = tid & 7;
    const ushort_t* src = bcbf + (size_t)(b * L_SEQ + c * CL + r) * 128;
    *reinterpret_cast<uint4*>(&bcs[r][q * 16]) =
        *reinterpret_cast<const uint4*>(src + q * 16);
    *reinterpret_cast<uint4*>(&bcs[r][q * 16 + 8]) =
        *reinterpret_cast<const uint4*>(src + q * 16 + 8);
    size_t rowb = (size_t)(b * L_SEQ + c * CL + r) * 256 + dq * 64 + q * 8;
    *reinterpret_cast<float4*>(&Ls[r][q * 8]) =
        *reinterpret_cast<const float4*>(&lamb[rowb]);
    *reinterpret_cast<float4*>(&Ls[r][q * 8 + 4]) =
        *reinterpret_cast<const float4*>(&lamb[rowb + 4]);
    *reinterpret_cast<uint4*>(&uws[r][q * 8]) =
        *reinterpret_cast<const uint4*>(uwb + rowb);
  }
  __syncthreads();

  // ---- G = C.B^T (4 tiles, 1/wave), mask tril, store bf16 ----
  {
    const int ti = w >> 1;
    const int tj = w & 1;
    f32x4 g = (f32x4){0.f, 0.f, 0.f, 0.f};
    #pragma unroll
    for (int ks = 0; ks < 2; ++ks) {
      const int ko = ks * 32 + rg * 8;
      bf16x8 aC = *reinterpret_cast<const bf16x8*>(&bcs[ti * 16 + row16][64 + ko]);
      bf16x8 bB = *reinterpret_cast<const bf16x8*>(&bcs[tj * 16 + row16][ko]);
      g = __builtin_amdgcn_mfma_f32_16x16x32_bf16(aC, bB, g, 0, 0, 0);
    }
    #pragma unroll
    for (int r = 0; r < 4; ++r) {
      const int t = ti * 16 + rg * 4 + r;
      const int tau = tj * 16 + cl;
      GL[t][tau] = (tau <= t) ? f2bf(g[r]) : (ushort_t)0;
    }
  }
  // ---- b^T build (all threads; reads bcs only) ----
  {
    #pragma unroll
    for (int k = 0; k < 8; ++k) {
      int el = tid * 8 + k;            // 0..2047
      int n = el >> 5;
      int tau = el & 31;
      bT[n][tau] = bcs[tau][n];
    }
  }
  // ---- cumprod L (4-segment parallel scan, all 256 threads) ----
  {
    const int d = tid & 63;
    const int seg = tid >> 6;
    float local = 1.f;
    #pragma unroll
    for (int k = 0; k < 8; ++k) {
      local *= Ls[seg * 8 + k][d];
      Ls[seg * 8 + k][d] = local;
    }
    segp[seg][d] = local;
  }
  __syncthreads();
  {
    const int d = tid & 63;
    const int seg = tid >> 6;
    float pre = 1.f;
    #pragma unroll
    for (int s = 0; s < 3; ++s)
      if (s < seg) pre *= segp[s][d];
    #pragma unroll
    for (int k = 0; k < 8; ++k) {
      const int t = seg * 8 + k;
      float L = Ls[t][d] * pre;
      Ls[t][d] = L;
      VT[d][t] = f2bf(bf2f(uws[t][d]) * __builtin_amdgcn_rcpf(L));
    }
  }
  __syncthreads();

  // ---- Y1 = tril(G).V, y_local = L .* Y1 (8 tiles, 2/wave) ----
  {
    const int ti = w & 1;
    #pragma unroll
    for (int p = 0; p < 2; ++p) {
      const int dj = (w >> 1) + p * 2;
      bf16x8 aG = *reinterpret_cast<const bf16x8*>(&GL[ti * 16 + row16][rg * 8]);
      bf16x8 bV = *reinterpret_cast<const bf16x8*>(&VT[dj * 16 + row16][rg * 8]);
      f32x4 y = __builtin_amdgcn_mfma_f32_16x16x32_bf16(aG, bV,
                  (f32x4){0.f, 0.f, 0.f, 0.f}, 0, 0, 0);
      #pragma unroll
      for (int r = 0; r < 4; ++r) {
        const int t = ti * 16 + rg * 4 + r;
        const int dcol = dj * 16 + cl;
        ylocal[(size_t)(b * L_SEQ + c * CL + t) * 256 + dq * 64 + dcol] =
            f2bf(Ls[t][dcol] * y[r]);
      }
    }
  }
  // ---- H_end = L_end .* (B^T.V) (16 tiles, 4/wave) ----
  {
    const int ni = w;
    bf16x8 aB = *reinterpret_cast<const bf16x8*>(&bT[ni * 16 + row16][rg * 8]);
    #pragma unroll
    for (int dj = 0; dj < 4; ++dj) {
      bf16x8 bV = *reinterpret_cast<const bf16x8*>(&VT[dj * 16 + row16][rg * 8]);
      f32x4 h = __builtin_amdgcn_mfma_f32_16x16x32_bf16(aB, bV,
                  (f32x4){0.f, 0.f, 0.f, 0.f}, 0, 0, 0);
      #pragma unroll
      for (int r = 0; r < 4; ++r) {
        const int n = ni * 16 + rg * 4 + r;
        const int dcol = dj * 16 + cl;
        Hc[((size_t)(b * NC + c) * 64 + n) * 256 + dq * 64 + dcol] =
            f2bf(Ls[CL - 1][dcol] * h[r]);
      }
    }
  }
  if (tid < 64)
    Pc[(size_t)(b * NC + c) * 256 + dq * 64 + tid] = Ls[CL - 1][tid];
}

// ---- K4: sequential chunk scan over NC=64, pipelined unroll-16 ------------
__global__ __launch_bounds__(128) void chunkscan(
    const float* __restrict__ Pc, ushort_t* __restrict__ Hc) {
  int tid = blockIdx.x * 128 + threadIdx.x;   // 32768 = B*N*D
  int d = tid & 255;
  int j = (tid >> 8) & 63;
  int b = tid >> 14;
  const size_t hstride = (size_t)N_DIM * 256;
  const size_t ihb = ((size_t)(b * NC) * 64 + j) * 256 + d;
  const size_t ipb = (size_t)(b * NC) * 256 + d;
  float h = 0.f;
  float Hv[16], Pv[16];
  #pragma unroll
  for (int q = 0; q < 16; ++q) {
    Hv[q] = bf2f(Hc[ihb + (size_t)q * hstride]);
    Pv[q] = Pc[ipb + (size_t)q * 256];
  }
  #pragma unroll 1
  for (int c0 = 0; c0 < NC; c0 += 16) {
    float Hn[16], Pn[16];
    if (c0 + 16 < NC) {
      #pragma unroll
      for (int q = 0; q < 16; ++q) {
        Hn[q] = bf2f(Hc[ihb + (size_t)(c0 + 16 + q) * hstride]);
        Pn[q] = Pc[ipb + (size_t)(c0 + 16 + q) * 256];
      }
    }
    #pragma unroll
    for (int q = 0; q < 16; ++q) {
      Hc[ihb + (size_t)(c0 + q) * hstride] = f2bf(h);
      h = fmaf(Pv[q], h, Hv[q]);
    }
    #pragma unroll
    for (int q = 0; q < 16; ++q) { Hv[q] = Hn[q]; Pv[q] = Pn[q]; }
  }
}

// ====== K5: cross-chunk correction via MFMA + GELU gate ====================
__global__ __launch_bounds__(256) void passB_mfma(
    const float* __restrict__ lamb, const ushort_t* __restrict__ bcbf,
    const ushort_t* __restrict__ hin, const ushort_t* __restrict__ skipb,
    const ushort_t* __restrict__ ylocal, ushort_t* __restrict__ gbf) {
  int b, c, dq;
  scan_decode(blockIdx.x, b, c, dq);
  const int tid = threadIdx.x;
  const int lane = tid & 63;
  const int w = tid >> 6;
  const int row16 = lane & 15;
  const int cl = lane & 15;
  const int rg = lane >> 4;

  __shared__ __align__(16) ushort_t cs[CL][72];   // c[t][n]
  __shared__ __align__(16) float    Ls[CL][68];   // lam -> cumprod
  __shared__ __align__(16) ushort_t HT[64][72];   // Hin^T[d][n]
  __shared__ float segp[4][68];

  {
    const int r = tid >> 3;
    const int q = tid & 7;
    *reinterpret_cast<uint4*>(&cs[r][q * 8]) =
        *reinterpret_cast<const uint4*>(
            bcbf + (size_t)(b * L_SEQ + c * CL + r) * 128 + 64 + q * 8);
    size_t rowb = (size_t)(b * L_SEQ + c * CL + r) * 256 + dq * 64 + q * 8;
    *reinterpret_cast<float4*>(&Ls[r][q * 8]) =
        *reinterpret_cast<const float4*>(&lamb[rowb]);
    *reinterpret_cast<float4*>(&Ls[r][q * 8 + 4]) =
        *reinterpret_cast<const float4*>(&lamb[rowb + 4]);
    #pragma unroll
    for (int nn = 0; nn < 2; ++nn) {
      const int n = (tid >> 3) + nn * 32;
      bf16x8 hv = *reinterpret_cast<const bf16x8*>(
          hin + ((size_t)(b * NC + c) * 64 + n) * 256 + dq * 64 + q * 8);
      #pragma unroll
      for (int k = 0; k < 8; ++k)
        HT[q * 8 + k][n] = (ushort_t)hv[k];
    }
  }
  __syncthreads();
  // ---- cumprod L (4-segment parallel scan) ----
  {
    const int d = tid & 63;
    const int seg = tid >> 6;
    float local = 1.f;
    #pragma unroll
    for (int k = 0; k < 8; ++k) {
      local *= Ls[seg * 8 + k][d];
      Ls[seg * 8 + k][d] = local;
    }
    segp[seg][d] = local;
  }
  __syncthreads();
  {
    const int d = tid & 63;
    const int seg = tid >> 6;
    float pre = 1.f;
    #pragma unroll
    for (int s = 0; s < 3; ++s)
      if (s < seg) pre *= segp[s][d];
    #pragma unroll
    for (int k = 0; k < 8; ++k) {
      const int t = seg * 8 + k;
      Ls[t][d] = Ls[t][d] * pre;
    }
  }
  __syncthreads();

  const int ti = w & 1;
  #pragma unroll
  for (int p = 0; p < 2; ++p) {
    const int dj = (w >> 1) + p * 2;
    f32x4 acc = (f32x4){0.f, 0.f, 0.f, 0.f};
    #pragma unroll
    for (int ks = 0; ks < 2; ++ks) {
      const int ko = ks * 32 + rg * 8;
      bf16x8 aC = *reinterpret_cast<const bf16x8*>(&cs[ti * 16 + row16][ko]);
      bf16x8 bH = *reinterpret_cast<const bf16x8*>(&HT[dj * 16 + row16][ko]);
      acc = __builtin_amdgcn_mfma_f32_16x16x32_bf16(aC, bH, acc, 0, 0, 0);
    }
    #pragma unroll
    for (int r = 0; r < 4; ++r) {
      const int t = ti * 16 + rg * 4 + r;
      const int dcol = dj * 16 + cl;
      size_t gi = (size_t)(b * L_SEQ + c * CL + t) * 256 + dq * 64 + dcol;
      float y = bf2f(ylocal[gi]) + Ls[t][dcol] * acc[r];
      float sk = bf2f(skipb[gi]);
      float g = 0.5f * sk * (1.f + erff(sk * 0.70710678118f));
      gbf[gi] = f2bf(g * y);
    }
  }
}

// ====== K6: out = g @ W_out^T, 64x64 tiles, XCD-swizzled ===================
__global__ __launch_bounds__(256) void mgemm64(
    const ushort_t* __restrict__ Ag, const ushort_t* __restrict__ Wg,
    float* __restrict__ C) {
  __shared__ __align__(16) ushort_t As[64][72];
  __shared__ __align__(16) ushort_t Ws[64][72];
  const int tid = threadIdx.x;
  const int lane = tid & 63;
  const int w = tid >> 6;
  const int wm = w >> 1;
  const int wn = w & 1;
  const int bid = blockIdx.x;
  const int bm = (bid & 63) * 64;
  const int bn = (bid >> 6) * 64;
  const int r0 = tid >> 3;
  const int c8 = (tid & 7) * 8;
  const int row16 = lane & 15;

  f32x4 acc[2][2];
  #pragma unroll
  for (int i = 0; i < 2; ++i)
    #pragma unroll
    for (int j = 0; j < 2; ++j)
      acc[i][j] = (f32x4){0.f, 0.f, 0.f, 0.f};

  for (int k0 = 0; k0 < 256; k0 += 64) {
    #pragma unroll
    for (int p = 0; p < 2; ++p) {
      int r = r0 + p * 32;
      *reinterpret_cast<uint4*>(&As[r][c8]) =
          *reinterpret_cast<const uint4*>(&Ag[(size_t)(bm + r) * 256 + k0 + c8]);
      *reinterpret_cast<uint4*>(&Ws[r][c8]) =
          *reinterpret_cast<const uint4*>(&Wg[(size_t)(bn + r) * 256 + k0 + c8]);
    }
    __syncthreads();
    #pragma unroll
    for (int ks = 0; ks < 2; ++ks) {
      const int ko = ks * 32 + (lane >> 4) * 8;
      bf16x8 af[2], bfr[2];
      #pragma unroll
      for (int i = 0; i < 2; ++i)
        af[i] = *reinterpret_cast<const bf16x8*>(&As[wm * 32 + i * 16 + row16][ko]);
      #pragma unroll
      for (int j = 0; j < 2; ++j)
        bfr[j] = *reinterpret_cast<const bf16x8*>(&Ws[wn * 32 + j * 16 + row16][ko]);
      #pragma unroll
      for (int i = 0; i < 2; ++i)
        #pragma unroll
        for (int j = 0; j < 2; ++j)
          acc[i][j] = __builtin_amdgcn_mfma_f32_16x16x32_bf16(af[i], bfr[j], acc[i][j], 0, 0, 0);
    }
    __syncthreads();
  }

  const int cl = lane & 15;
  const int rg = lane >> 4;
  #pragma unroll
  for (int j = 0; j < 2; ++j) {
    const int col = bn + wn * 32 + j * 16 + cl;
    #pragma unroll
    for (int i = 0; i < 2; ++i) {
      const int rbase = bm + wm * 32 + i * 16 + rg * 4;
      #pragma unroll
      for (int rr = 0; rr < 4; ++rr)
        C[(size_t)(rbase + rr) * 256 + col] = acc[i][j][rr];
    }
  }
}

extern "C" void kernel_launch(void* const* d_in, const int* in_sizes, int n_in,
                              void* d_out, int out_size, void* d_ws, size_t ws_size,
                              hipStream_t stream) {
  const float* x      = (const float*)d_in[0];
  const float* W_in   = (const float*)d_in[1];
  const float* conv_w = (const float*)d_in[2];
  const float* conv_b = (const float*)d_in[3];
  const float* W_bc   = (const float*)d_in[4];
  const float* b_bc   = (const float*)d_in[5];
  const float* W_lam  = (const float*)d_in[6];
  const float* b_lam  = (const float*)d_in[7];
  const float* A      = (const float*)d_in[8];
  const float* W_out  = (const float*)d_in[9];
  float* out = (float*)d_out;

  float* ws = (float*)d_ws;
  ushort_t* skipb  = (ushort_t*)(ws + 0);        // 1,048,576 sh
  ushort_t* praw   = (ushort_t*)(ws + 524288);   // 1,048,576 sh
  float*    lamb   = ws + 1048576;               // 1,048,576 f
  ushort_t* uwb    = (ushort_t*)(ws + 2097152);  // 1,048,576 sh
  ushort_t* bcbf   = (ushort_t*)(ws + 2621440);  //   524,288 sh
  ushort_t* ylocal = (ushort_t*)(ws + 2883584);  // 1,048,576 sh
  float*    Pc     = ws + 3407872;               //    32,768 f
  ushort_t* Hc     = (ushort_t*)(ws + 3440640);  // 2,097,152 sh
  ushort_t* wbcb   = (ushort_t*)(ws + 4489216);  //    32,768 sh
  ushort_t* wlb    = (ushort_t*)(ws + 4505600);  //    65,536 sh
  ushort_t* wob    = (ushort_t*)(ws + 4538368);  //    65,536 sh
  ushort_t* gbf    = (ushort_t*)(ws + 4571136);  // 1,048,576 sh
  // end: 5,095,424 floats ~ 20.4 MB

  // 1) proj = x @ W_in^T (inline cvt) + weight conversions  [672 blocks]
  projcvt64<<<dim3(672), dim3(256), 0, stream>>>(
      x, W_in, W_bc, W_lam, W_out, wbcb, wlb, wob, skipb, praw);
  // 2) conv (LDS) + fused bc|lambda GEMM (64-row panels)    [384 blocks]
  convbclam<<<dim3(384), dim3(256), 0, stream>>>(
      praw, conv_w, conv_b, wbcb, wlb, b_bc, b_lam, A, bcbf, lamb, uwb);
  // 3) chunk-local scan via MFMA (producer-aligned XCD map) [512 blocks]
  passA_mfma<<<dim3(B_DIM * NC * 4), dim3(256), 0, stream>>>(
      lamb, uwb, bcbf, Pc, Hc, ylocal);
  // 4) chunk-prefix scan                                    [256 blocks]
  chunkscan<<<dim3(256), dim3(128), 0, stream>>>(Pc, Hc);
  // 5) cross-chunk correction + gelu (producer-aligned)     [512 blocks]
  passB_mfma<<<dim3(B_DIM * NC * 4), dim3(256), 0, stream>>>(
      lamb, bcbf, Hc, skipb, ylocal, gbf);
  // 6) out = g @ W_out^T                                    [256 blocks]
  mgemm64<<<dim3(256), dim3(256), 0, stream>>>(gbf, wob, out);
}

// Round 18
// 44.611 us; speedup vs baseline: 1.0094x; 1.0094x over previous
//
#include <hip/hip_runtime.h>
#include <hip/hip_bf16.h>
#include <math.h>

// Problem constants
#define B_DIM 2
#define L_SEQ 2048
#define D_DIM 256
#define N_DIM 64
#define K_CONV 4
#define M_ROWS (B_DIM * L_SEQ)   // 4096
#define NC 64                     // number of scan chunks
#define CL (L_SEQ / NC)           // 32 steps per chunk

typedef __attribute__((ext_vector_type(8))) short bf16x8;
typedef __attribute__((ext_vector_type(4))) float f32x4;
typedef unsigned short ushort_t;

static __device__ __forceinline__ unsigned short f2bf(float f) {
  unsigned int u = __float_as_uint(f);
  unsigned int r = u + 0x7FFF + ((u >> 16) & 1);   // round-to-nearest-even
  return (unsigned short)(r >> 16);
}
static __device__ __forceinline__ float bf2f(ushort_t s) {
  return __uint_as_float(((unsigned int)s) << 16);
}
static __device__ __forceinline__ unsigned int pack2(float a, float b) {
  return (unsigned int)f2bf(a) | ((unsigned int)f2bf(b) << 16);
}

// ====== K1: proj = x @ W_in^T (inline f32->bf16 staging) + weight cvt ======
// blocks 0..511: 64x64 GEMM tiles, XCD-swizzled (bm = bid&63 -> same-panel
// blocks share an XCD; row panel p lives on XCD p%8).
// blocks 512..671: convert W_bc/W_lam/W_out to bf16.
__global__ __launch_bounds__(256) void projcvt64(
    const float* __restrict__ x, const float* __restrict__ wi,
    const float* __restrict__ wbc, const float* __restrict__ wl,
    const float* __restrict__ wo,
    ushort_t* __restrict__ wbcb, ushort_t* __restrict__ wlb,
    ushort_t* __restrict__ wob,
    ushort_t* __restrict__ skipb, ushort_t* __restrict__ praw) {
  const int bid = blockIdx.x;
  const int tid = threadIdx.x;
  if (bid >= 512) {                 // ---- converter blocks ----
    int vb = bid - 512;
    const float* src; ushort_t* dst; int off;
    if (vb < 32)      { src = wbc; dst = wbcb; off = vb; }
    else if (vb < 96) { src = wl;  dst = wlb;  off = vb - 32; }
    else              { src = wo;  dst = wob;  off = vb - 96; }
    size_t i = (size_t)off * 1024 + tid * 4;
    float4 v = *reinterpret_cast<const float4*>(&src[i]);
    ushort4 o;
    o.x = f2bf(v.x); o.y = f2bf(v.y); o.z = f2bf(v.z); o.w = f2bf(v.w);
    *reinterpret_cast<ushort4*>(&dst[i]) = o;
    return;
  }
  // ---- GEMM block ----
  __shared__ __align__(16) ushort_t As[64][72];
  __shared__ __align__(16) ushort_t Ws[64][72];
  const int lane = tid & 63;
  const int w = tid >> 6;
  const int wm = w >> 1;
  const int wn = w & 1;
  const int bm = (bid & 63) * 64;
  const int bn = (bid >> 6) * 64;
  const int r0 = tid >> 3;          // 0..31
  const int c8 = (tid & 7) * 8;
  const int row16 = lane & 15;

  f32x4 acc[2][2];
  #pragma unroll
  for (int i = 0; i < 2; ++i)
    #pragma unroll
    for (int j = 0; j < 2; ++j)
      acc[i][j] = (f32x4){0.f, 0.f, 0.f, 0.f};

  for (int k0 = 0; k0 < 256; k0 += 64) {
    #pragma unroll
    for (int p = 0; p < 2; ++p) {
      int r = r0 + p * 32;
      const float* src = &x[(size_t)(bm + r) * 256 + k0 + c8];
      float4 v0 = *reinterpret_cast<const float4*>(src);
      float4 v1 = *reinterpret_cast<const float4*>(src + 4);
      uint4 o;
      o.x = pack2(v0.x, v0.y); o.y = pack2(v0.z, v0.w);
      o.z = pack2(v1.x, v1.y); o.w = pack2(v1.z, v1.w);
      *reinterpret_cast<uint4*>(&As[r][c8]) = o;
      const float* srcw = &wi[(size_t)(bn + r) * 256 + k0 + c8];
      float4 w0 = *reinterpret_cast<const float4*>(srcw);
      float4 w1 = *reinterpret_cast<const float4*>(srcw + 4);
      uint4 ow;
      ow.x = pack2(w0.x, w0.y); ow.y = pack2(w0.z, w0.w);
      ow.z = pack2(w1.x, w1.y); ow.w = pack2(w1.z, w1.w);
      *reinterpret_cast<uint4*>(&Ws[r][c8]) = ow;
    }
    __syncthreads();
    #pragma unroll
    for (int ks = 0; ks < 2; ++ks) {
      const int ko = ks * 32 + (lane >> 4) * 8;
      bf16x8 af[2], bfr[2];
      #pragma unroll
      for (int i = 0; i < 2; ++i)
        af[i] = *reinterpret_cast<const bf16x8*>(&As[wm * 32 + i * 16 + row16][ko]);
      #pragma unroll
      for (int j = 0; j < 2; ++j)
        bfr[j] = *reinterpret_cast<const bf16x8*>(&Ws[wn * 32 + j * 16 + row16][ko]);
      #pragma unroll
      for (int i = 0; i < 2; ++i)
        #pragma unroll
        for (int j = 0; j < 2; ++j)
          acc[i][j] = __builtin_amdgcn_mfma_f32_16x16x32_bf16(af[i], bfr[j], acc[i][j], 0, 0, 0);
    }
    __syncthreads();
  }

  const int cl = lane & 15;
  const int rg = lane >> 4;
  #pragma unroll
  for (int j = 0; j < 2; ++j) {
    const int col = bn + wn * 32 + j * 16 + cl;
    ushort_t* dst = (col < 256) ? skipb : praw;
    const int cc = col & 255;
    #pragma unroll
    for (int i = 0; i < 2; ++i) {
      const int rbase = bm + wm * 32 + i * 16 + rg * 4;
      #pragma unroll
      for (int rr = 0; rr < 4; ++rr)
        dst[(size_t)(rbase + rr) * 256 + cc] = f2bf(acc[i][j][rr]);
    }
  }
}

// ====== K2: depthwise conv (into LDS) + bc|lambda GEMM, 64-row panels ======
// bm = (bid&63)*64 -> row panel bid&63 stays on XCD (bid&63)%8 = producer's.
__global__ __launch_bounds__(256) void convbclam(
    const ushort_t* __restrict__ praw, const float* __restrict__ cw,
    const float* __restrict__ cb,
    const ushort_t* __restrict__ wbcb, const ushort_t* __restrict__ wlb,
    const float* __restrict__ b_bc, const float* __restrict__ b_lam,
    const float* __restrict__ Avec,
    ushort_t* __restrict__ bcbf, float* __restrict__ lamb,
    ushort_t* __restrict__ uwb) {
  __shared__ __align__(16) ushort_t Us[64][264];    // 33.8 KB
  __shared__ __align__(16) ushort_t Ws[64][72];     // 9.2 KB
  const int tid = threadIdx.x;
  const int lane = tid & 63;
  const int w = tid >> 6;
  const int wm = w >> 1;
  const int wn = w & 1;
  const int bid = blockIdx.x;
  const int bm = (bid & 63) * 64;
  const int bn = (bid >> 6) * 64;    // 0..5 tiles

  {
    const int d = tid;
    const float4 w4 = *reinterpret_cast<const float4*>(&cw[d * 4]);
    const float bias = cb[d];
    const bool edge = (bm & 2047) == 0;   // batch boundary
    float p0 = edge ? 0.f : bf2f(praw[(size_t)(bm - 3) * 256 + d]);
    float p1 = edge ? 0.f : bf2f(praw[(size_t)(bm - 2) * 256 + d]);
    float p2 = edge ? 0.f : bf2f(praw[(size_t)(bm - 1) * 256 + d]);
    #pragma unroll 8
    for (int r = 0; r < 64; ++r) {
      float p3 = bf2f(praw[(size_t)(bm + r) * 256 + d]);
      float u = bias + w4.x * p0 + w4.y * p1 + w4.z * p2 + w4.w * p3;
      Us[r][d] = f2bf(u);
      p0 = p1; p1 = p2; p2 = p3;
    }
  }
  __syncthreads();

  const ushort_t* Wsrc = (bn < 128) ? (wbcb + (size_t)bn * 256)
                                    : (wlb + (size_t)(bn - 128) * 256);
  const int r0 = tid >> 3;
  const int c8 = (tid & 7) * 8;
  const int row16 = lane & 15;

  f32x4 acc[2][2];
  #pragma unroll
  for (int i = 0; i < 2; ++i)
    #pragma unroll
    for (int j = 0; j < 2; ++j)
      acc[i][j] = (f32x4){0.f, 0.f, 0.f, 0.f};

  for (int k0 = 0; k0 < 256; k0 += 64) {
    #pragma unroll
    for (int p = 0; p < 2; ++p) {
      int r = r0 + p * 32;
      uint4 v = *reinterpret_cast<const uint4*>(&Wsrc[(size_t)r * 256 + k0 + c8]);
      *reinterpret_cast<uint4*>(&Ws[r][c8]) = v;
    }
    __syncthreads();
    #pragma unroll
    for (int ks = 0; ks < 2; ++ks) {
      const int ko = ks * 32 + (lane >> 4) * 8;
      bf16x8 af[2], bfr[2];
      #pragma unroll
      for (int i = 0; i < 2; ++i)
        af[i] = *reinterpret_cast<const bf16x8*>(&Us[wm * 32 + i * 16 + row16][k0 + ko]);
      #pragma unroll
      for (int j = 0; j < 2; ++j)
        bfr[j] = *reinterpret_cast<const bf16x8*>(&Ws[wn * 32 + j * 16 + row16][ko]);
      #pragma unroll
      for (int i = 0; i < 2; ++i)
        #pragma unroll
        for (int j = 0; j < 2; ++j)
          acc[i][j] = __builtin_amdgcn_mfma_f32_16x16x32_bf16(af[i], bfr[j], acc[i][j], 0, 0, 0);
    }
    __syncthreads();
  }

  const int cl = lane & 15;
  const int rg = lane >> 4;
  #pragma unroll
  for (int j = 0; j < 2; ++j) {
    const int col = bn + wn * 32 + j * 16 + cl;
    if (col < 128) {
      const float bv = b_bc[col];
      #pragma unroll
      for (int i = 0; i < 2; ++i) {
        const int rbase = bm + wm * 32 + i * 16 + rg * 4;
        #pragma unroll
        for (int rr = 0; rr < 4; ++rr)
          bcbf[(size_t)(rbase + rr) * 128 + col] = f2bf(acc[i][j][rr] + bv);
      }
    } else {
      const int dd = col - 128;
      const float bv = b_lam[dd];
      const float adg = -8.f * log1pf(__expf(Avec[dd]));
      #pragma unroll
      for (int i = 0; i < 2; ++i) {
        const int rbase = bm + wm * 32 + i * 16 + rg * 4;
        #pragma unroll
        for (int rr = 0; rr < 4; ++rr) {
          const int row = rbase + rr;
          float v = acc[i][j][rr] + bv;
          float s = 1.f / (1.f + __expf(-v));
          float lam = __expf(s * adg);
          float wq = sqrtf(1.f + 1e-6f - lam * lam);
          float u = bf2f(Us[row - bm][dd]);
          lamb[(size_t)row * 256 + dd] = lam;
          uwb[(size_t)row * 256 + dd] = f2bf(u * wq);
        }
      }
    }
  }
}

// ---- producer-aligned decode for the scan kernels -------------------------
// Chunk c occupies row panel c/2, produced on XCD (c/2)%8. Map blocks so
// chunk c runs on XCD (c/2)%8: xcd = bid&7, c = 2*(xcd + 8*pair) + parity.
static __device__ __forceinline__ void scan_decode(
    int bid, int& b, int& c, int& dq) {
  const int xcd = bid & 7;
  const int idx = bid >> 3;      // 0..63
  b = idx >> 5;                  // 0..1
  const int rem = idx & 31;      // 0..31
  c = 2 * (xcd + 8 * (rem & 3)) + ((rem >> 2) & 1);
  dq = (rem >> 3) & 3;
}

// ====== K3: chunk-local scan via MFMA (chunked linear attention) ===========
__global__ __launch_bounds__(256) void passA_mfma(
    const float* __restrict__ lamb, const ushort_t* __restrict__ uwb,
    const ushort_t* __restrict__ bcbf, float* __restrict__ Pc,
    ushort_t* __restrict__ Hc, ushort_t* __restrict__ ylocal) {
  int b, c, dq;
  scan_decode(blockIdx.x, b, c, dq);
  const int tid = threadIdx.x;
  const int lane = tid & 63;
  const int w = tid >> 6;
  const int row16 = lane & 15;
  const int cl = lane & 15;
  const int rg = lane >> 4;

  __shared__ __align__(16) ushort_t bcs[CL][136];  // [t][0..63]=b, [64..127]=c
  __shared__ __align__(16) float    Ls[CL][68];    // lam -> cumprod (in place)
  __shared__ __align__(16) ushort_t uws[CL][72];
  __shared__ __align__(16) ushort_t VT[64][40];    // V^T[d][tau]
  __shared__ __align__(16) ushort_t bT[64][40];    // b^T[n][tau]
  __shared__ __align__(16) ushort_t GL[CL][40];    // tril(G)[t][tau]
  __shared__ float segp[4][68];

  {
    const int r = tid >> 3;
    const int q = tid & 7;
    const ushort_t* src = bcbf + (size_t)(b * L_SEQ + c * CL + r) * 128;
    *reinterpret_cast<uint4*>(&bcs[r][q * 16]) =
        *reinterpret_cast<const uint4*>(src + q * 16);
    *reinterpret_cast<uint4*>(&bcs[r][q * 16 + 8]) =
        *reinterpret_cast<const uint4*>(src + q * 16 + 8);
    size_t rowb = (size_t)(b * L_SEQ + c * CL + r) * 256 + dq * 64 + q * 8;
    *reinterpret_cast<float4*>(&Ls[r][q * 8]) =
        *reinterpret_cast<const float4*>(&lamb[rowb]);
    *reinterpret_cast<float4*>(&Ls[r][q * 8 + 4]) =
        *reinterpret_cast<const float4*>(&lamb[rowb + 4]);
    *reinterpret_cast<uint4*>(&uws[r][q * 8]) =
        *reinterpret_cast<const uint4*>(uwb + rowb);
  }
  __syncthreads();

  // ---- G = C.B^T (4 tiles, 1/wave), mask tril, store bf16 ----
  {
    const int ti = w >> 1;
    const int tj = w & 1;
    f32x4 g = (f32x4){0.f, 0.f, 0.f, 0.f};
    #pragma unroll
    for (int ks = 0; ks < 2; ++ks) {
      const int ko = ks * 32 + rg * 8;
      bf16x8 aC = *reinterpret_cast<const bf16x8*>(&bcs[ti * 16 + row16][64 + ko]);
      bf16x8 bB = *reinterpret_cast<const bf16x8*>(&bcs[tj * 16 + row16][ko]);
      g = __builtin_amdgcn_mfma_f32_16x16x32_bf16(aC, bB, g, 0, 0, 0);
    }
    #pragma unroll
    for (int r = 0; r < 4; ++r) {
      const int t = ti * 16 + rg * 4 + r;
      const int tau = tj * 16 + cl;
      GL[t][tau] = (tau <= t) ? f2bf(g[r]) : (ushort_t)0;
    }
  }
  // ---- b^T build (all threads; reads bcs only) ----
  {
    #pragma unroll
    for (int k = 0; k < 8; ++k) {
      int el = tid * 8 + k;            // 0..2047
      int n = el >> 5;
      int tau = el & 31;
      bT[n][tau] = bcs[tau][n];
    }
  }
  // ---- cumprod L (4-segment parallel scan, all 256 threads) ----
  {
    const int d = tid & 63;
    const int seg = tid >> 6;
    float local = 1.f;
    #pragma unroll
    for (int k = 0; k < 8; ++k) {
      local *= Ls[seg * 8 + k][d];
      Ls[seg * 8 + k][d] = local;
    }
    segp[seg][d] = local;
  }
  __syncthreads();
  {
    const int d = tid & 63;
    const int seg = tid >> 6;
    float pre = 1.f;
    #pragma unroll
    for (int s = 0; s < 3; ++s)
      if (s < seg) pre *= segp[s][d];
    #pragma unroll
    for (int k = 0; k < 8; ++k) {
      const int t = seg * 8 + k;
      float L = Ls[t][d] * pre;
      Ls[t][d] = L;
      VT[d][t] = f2bf(bf2f(uws[t][d]) / L);
    }
  }
  __syncthreads();

  // ---- Y1 = tril(G).V, y_local = L .* Y1 (8 tiles, 2/wave) ----
  {
    const int ti = w & 1;
    #pragma unroll
    for (int p = 0; p < 2; ++p) {
      const int dj = (w >> 1) + p * 2;
      bf16x8 aG = *reinterpret_cast<const bf16x8*>(&GL[ti * 16 + row16][rg * 8]);
      bf16x8 bV = *reinterpret_cast<const bf16x8*>(&VT[dj * 16 + row16][rg * 8]);
      f32x4 y = __builtin_amdgcn_mfma_f32_16x16x32_bf16(aG, bV,
                  (f32x4){0.f, 0.f, 0.f, 0.f}, 0, 0, 0);
      #pragma unroll
      for (int r = 0; r < 4; ++r) {
        const int t = ti * 16 + rg * 4 + r;
        const int dcol = dj * 16 + cl;
        ylocal[(size_t)(b * L_SEQ + c * CL + t) * 256 + dq * 64 + dcol] =
            f2bf(Ls[t][dcol] * y[r]);
      }
    }
  }
  // ---- H_end = L_end .* (B^T.V) (16 tiles, 4/wave) ----
  {
    const int ni = w;
    bf16x8 aB = *reinterpret_cast<const bf16x8*>(&bT[ni * 16 + row16][rg * 8]);
    #pragma unroll
    for (int dj = 0; dj < 4; ++dj) {
      bf16x8 bV = *reinterpret_cast<const bf16x8*>(&VT[dj * 16 + row16][rg * 8]);
      f32x4 h = __builtin_amdgcn_mfma_f32_16x16x32_bf16(aB, bV,
                  (f32x4){0.f, 0.f, 0.f, 0.f}, 0, 0, 0);
      #pragma unroll
      for (int r = 0; r < 4; ++r) {
        const int n = ni * 16 + rg * 4 + r;
        const int dcol = dj * 16 + cl;
        Hc[((size_t)(b * NC + c) * 64 + n) * 256 + dq * 64 + dcol] =
            f2bf(Ls[CL - 1][dcol] * h[r]);
      }
    }
  }
  if (tid < 64)
    Pc[(size_t)(b * NC + c) * 256 + dq * 64 + tid] = Ls[CL - 1][tid];
}

// ---- K4: sequential chunk scan over NC=64, pipelined unroll-16 ------------
__global__ __launch_bounds__(128) void chunkscan(
    const float* __restrict__ Pc, ushort_t* __restrict__ Hc) {
  int tid = blockIdx.x * 128 + threadIdx.x;   // 32768 = B*N*D
  int d = tid & 255;
  int j = (tid >> 8) & 63;
  int b = tid >> 14;
  const size_t hstride = (size_t)N_DIM * 256;
  const size_t ihb = ((size_t)(b * NC) * 64 + j) * 256 + d;
  const size_t ipb = (size_t)(b * NC) * 256 + d;
  float h = 0.f;
  float Hv[16], Pv[16];
  #pragma unroll
  for (int q = 0; q < 16; ++q) {
    Hv[q] = bf2f(Hc[ihb + (size_t)q * hstride]);
    Pv[q] = Pc[ipb + (size_t)q * 256];
  }
  #pragma unroll 1
  for (int c0 = 0; c0 < NC; c0 += 16) {
    float Hn[16], Pn[16];
    if (c0 + 16 < NC) {
      #pragma unroll
      for (int q = 0; q < 16; ++q) {
        Hn[q] = bf2f(Hc[ihb + (size_t)(c0 + 16 + q) * hstride]);
        Pn[q] = Pc[ipb + (size_t)(c0 + 16 + q) * 256];
      }
    }
    #pragma unroll
    for (int q = 0; q < 16; ++q) {
      Hc[ihb + (size_t)(c0 + q) * hstride] = f2bf(h);
      h = fmaf(Pv[q], h, Hv[q]);
    }
    #pragma unroll
    for (int q = 0; q < 16; ++q) { Hv[q] = Hn[q]; Pv[q] = Pn[q]; }
  }
}

// ====== K5: cross-chunk correction via MFMA + GELU gate ====================
__global__ __launch_bounds__(256) void passB_mfma(
    const float* __restrict__ lamb, const ushort_t* __restrict__ bcbf,
    const ushort_t* __restrict__ hin, const ushort_t* __restrict__ skipb,
    const ushort_t* __restrict__ ylocal, ushort_t* __restrict__ gbf) {
  int b, c, dq;
  scan_decode(blockIdx.x, b, c, dq);
  const int tid = threadIdx.x;
  const int lane = tid & 63;
  const int w = tid >> 6;
  const int row16 = lane & 15;
  const int cl = lane & 15;
  const int rg = lane >> 4;

  __shared__ __align__(16) ushort_t cs[CL][72];   // c[t][n]
  __shared__ __align__(16) float    Ls[CL][68];   // lam -> cumprod
  __shared__ __align__(16) ushort_t HT[64][72];   // Hin^T[d][n]
  __shared__ float segp[4][68];

  {
    const int r = tid >> 3;
    const int q = tid & 7;
    *reinterpret_cast<uint4*>(&cs[r][q * 8]) =
        *reinterpret_cast<const uint4*>(
            bcbf + (size_t)(b * L_SEQ + c * CL + r) * 128 + 64 + q * 8);
    size_t rowb = (size_t)(b * L_SEQ + c * CL + r) * 256 + dq * 64 + q * 8;
    *reinterpret_cast<float4*>(&Ls[r][q * 8]) =
        *reinterpret_cast<const float4*>(&lamb[rowb]);
    *reinterpret_cast<float4*>(&Ls[r][q * 8 + 4]) =
        *reinterpret_cast<const float4*>(&lamb[rowb + 4]);
    #pragma unroll
    for (int nn = 0; nn < 2; ++nn) {
      const int n = (tid >> 3) + nn * 32;
      bf16x8 hv = *reinterpret_cast<const bf16x8*>(
          hin + ((size_t)(b * NC + c) * 64 + n) * 256 + dq * 64 + q * 8);
      #pragma unroll
      for (int k = 0; k < 8; ++k)
        HT[q * 8 + k][n] = (ushort_t)hv[k];
    }
  }
  __syncthreads();
  // ---- cumprod L (4-segment parallel scan) ----
  {
    const int d = tid & 63;
    const int seg = tid >> 6;
    float local = 1.f;
    #pragma unroll
    for (int k = 0; k < 8; ++k) {
      local *= Ls[seg * 8 + k][d];
      Ls[seg * 8 + k][d] = local;
    }
    segp[seg][d] = local;
  }
  __syncthreads();
  {
    const int d = tid & 63;
    const int seg = tid >> 6;
    float pre = 1.f;
    #pragma unroll
    for (int s = 0; s < 3; ++s)
      if (s < seg) pre *= segp[s][d];
    #pragma unroll
    for (int k = 0; k < 8; ++k) {
      const int t = seg * 8 + k;
      Ls[t][d] = Ls[t][d] * pre;
    }
  }
  __syncthreads();

  const int ti = w & 1;
  #pragma unroll
  for (int p = 0; p < 2; ++p) {
    const int dj = (w >> 1) + p * 2;
    f32x4 acc = (f32x4){0.f, 0.f, 0.f, 0.f};
    #pragma unroll
    for (int ks = 0; ks < 2; ++ks) {
      const int ko = ks * 32 + rg * 8;
      bf16x8 aC = *reinterpret_cast<const bf16x8*>(&cs[ti * 16 + row16][ko]);
      bf16x8 bH = *reinterpret_cast<const bf16x8*>(&HT[dj * 16 + row16][ko]);
      acc = __builtin_amdgcn_mfma_f32_16x16x32_bf16(aC, bH, acc, 0, 0, 0);
    }
    #pragma unroll
    for (int r = 0; r < 4; ++r) {
      const int t = ti * 16 + rg * 4 + r;
      const int dcol = dj * 16 + cl;
      size_t gi = (size_t)(b * L_SEQ + c * CL + t) * 256 + dq * 64 + dcol;
      float y = bf2f(ylocal[gi]) + Ls[t][dcol] * acc[r];
      float sk = bf2f(skipb[gi]);
      float g = 0.5f * sk * (1.f + erff(sk * 0.70710678118f));
      gbf[gi] = f2bf(g * y);
    }
  }
}

// ====== K6: out = g @ W_out^T, 64x64 tiles, XCD-swizzled ===================
__global__ __launch_bounds__(256) void mgemm64(
    const ushort_t* __restrict__ Ag, const ushort_t* __restrict__ Wg,
    float* __restrict__ C) {
  __shared__ __align__(16) ushort_t As[64][72];
  __shared__ __align__(16) ushort_t Ws[64][72];
  const int tid = threadIdx.x;
  const int lane = tid & 63;
  const int w = tid >> 6;
  const int wm = w >> 1;
  const int wn = w & 1;
  const int bid = blockIdx.x;
  const int bm = (bid & 63) * 64;
  const int bn = (bid >> 6) * 64;
  const int r0 = tid >> 3;
  const int c8 = (tid & 7) * 8;
  const int row16 = lane & 15;

  f32x4 acc[2][2];
  #pragma unroll
  for (int i = 0; i < 2; ++i)
    #pragma unroll
    for (int j = 0; j < 2; ++j)
      acc[i][j] = (f32x4){0.f, 0.f, 0.f, 0.f};

  for (int k0 = 0; k0 < 256; k0 += 64) {
    #pragma unroll
    for (int p = 0; p < 2; ++p) {
      int r = r0 + p * 32;
      *reinterpret_cast<uint4*>(&As[r][c8]) =
          *reinterpret_cast<const uint4*>(&Ag[(size_t)(bm + r) * 256 + k0 + c8]);
      *reinterpret_cast<uint4*>(&Ws[r][c8]) =
          *reinterpret_cast<const uint4*>(&Wg[(size_t)(bn + r) * 256 + k0 + c8]);
    }
    __syncthreads();
    #pragma unroll
    for (int ks = 0; ks < 2; ++ks) {
      const int ko = ks * 32 + (lane >> 4) * 8;
      bf16x8 af[2], bfr[2];
      #pragma unroll
      for (int i = 0; i < 2; ++i)
        af[i] = *reinterpret_cast<const bf16x8*>(&As[wm * 32 + i * 16 + row16][ko]);
      #pragma unroll
      for (int j = 0; j < 2; ++j)
        bfr[j] = *reinterpret_cast<const bf16x8*>(&Ws[wn * 32 + j * 16 + row16][ko]);
      #pragma unroll
      for (int i = 0; i < 2; ++i)
        #pragma unroll
        for (int j = 0; j < 2; ++j)
          acc[i][j] = __builtin_amdgcn_mfma_f32_16x16x32_bf16(af[i], bfr[j], acc[i][j], 0, 0, 0);
    }
    __syncthreads();
  }

  const int cl = lane & 15;
  const int rg = lane >> 4;
  #pragma unroll
  for (int j = 0; j < 2; ++j) {
    const int col = bn + wn * 32 + j * 16 + cl;
    #pragma unroll
    for (int i = 0; i < 2; ++i) {
      const int rbase = bm + wm * 32 + i * 16 + rg * 4;
      #pragma unroll
      for (int rr = 0; rr < 4; ++rr)
        C[(size_t)(rbase + rr) * 256 + col] = acc[i][j][rr];
    }
  }
}

extern "C" void kernel_launch(void* const* d_in, const int* in_sizes, int n_in,
                              void* d_out, int out_size, void* d_ws, size_t ws_size,
                              hipStream_t stream) {
  const float* x      = (const float*)d_in[0];
  const float* W_in   = (const float*)d_in[1];
  const float* conv_w = (const float*)d_in[2];
  const float* conv_b = (const float*)d_in[3];
  const float* W_bc   = (const float*)d_in[4];
  const float* b_bc   = (const float*)d_in[5];
  const float* W_lam  = (const float*)d_in[6];
  const float* b_lam  = (const float*)d_in[7];
  const float* A      = (const float*)d_in[8];
  const float* W_out  = (const float*)d_in[9];
  float* out = (float*)d_out;

  float* ws = (float*)d_ws;
  ushort_t* skipb  = (ushort_t*)(ws + 0);        // 1,048,576 sh
  ushort_t* praw   = (ushort_t*)(ws + 524288);   // 1,048,576 sh
  float*    lamb   = ws + 1048576;               // 1,048,576 f
  ushort_t* uwb    = (ushort_t*)(ws + 2097152);  // 1,048,576 sh
  ushort_t* bcbf   = (ushort_t*)(ws + 2621440);  //   524,288 sh
  ushort_t* ylocal = (ushort_t*)(ws + 2883584);  // 1,048,576 sh
  float*    Pc     = ws + 3407872;               //    32,768 f
  ushort_t* Hc     = (ushort_t*)(ws + 3440640);  // 2,097,152 sh
  ushort_t* wbcb   = (ushort_t*)(ws + 4489216);  //    32,768 sh
  ushort_t* wlb    = (ushort_t*)(ws + 4505600);  //    65,536 sh
  ushort_t* wob    = (ushort_t*)(ws + 4538368);  //    65,536 sh
  ushort_t* gbf    = (ushort_t*)(ws + 4571136);  // 1,048,576 sh
  // end: 5,095,424 floats ~ 20.4 MB

  // 1) proj = x @ W_in^T (inline cvt) + weight conversions  [672 blocks]
  projcvt64<<<dim3(672), dim3(256), 0, stream>>>(
      x, W_in, W_bc, W_lam, W_out, wbcb, wlb, wob, skipb, praw);
  // 2) conv (LDS) + fused bc|lambda GEMM (64-row panels)    [384 blocks]
  convbclam<<<dim3(384), dim3(256), 0, stream>>>(
      praw, conv_w, conv_b, wbcb, wlb, b_bc, b_lam, A, bcbf, lamb, uwb);
  // 3) chunk-local scan via MFMA (producer-aligned XCD map) [512 blocks]
  passA_mfma<<<dim3(B_DIM * NC * 4), dim3(256), 0, stream>>>(
      lamb, uwb, bcbf, Pc, Hc, ylocal);
  // 4) chunk-prefix scan                                    [256 blocks]
  chunkscan<<<dim3(256), dim3(128), 0, stream>>>(Pc, Hc);
  // 5) cross-chunk correction + gelu (producer-aligned)     [512 blocks]
  passB_mfma<<<dim3(B_DIM * NC * 4), dim3(256), 0, stream>>>(
      lamb, bcbf, Hc, skipb, ylocal, gbf);
  // 6) out = g @ W_out^T                                    [256 blocks]
  mgemm64<<<dim3(256), dim3(256), 0, stream>>>(gbf, wob, out);
}